// Round 1
// baseline (52.758 us; speedup 1.0000x reference)
//
#include <hip/hip_runtime.h>

// x: (B=8, C=128, T=8, H=56, W=56) fp32
// out[b, t, c, h, w] = w0*x[b,c,t-1,h,w] + w1*x[b,c,t,h,w] + w2*x[b,c,t+1,h,w] + bias
// (zero-padded at t boundaries), out shape (B*T, C, H, W) fp32.

#define B_  8
#define C_  128
#define T_  8
#define HW4 784            // (56*56)/4 float4 per plane
#define TOT4 (B_ * T_ * C_ * HW4)   // 6,422,528 float4 outputs

__global__ __launch_bounds__(256) void temporal_interaction_kernel(
    const float4* __restrict__ in4,
    const float* __restrict__ cw,
    const float* __restrict__ cb,
    float4* __restrict__ out4)
{
    const float w0 = cw[0];
    const float w1 = cw[1];
    const float w2 = cw[2];
    const float bs = cb[0];

    const int stride = gridDim.x * blockDim.x;
    for (int i = blockIdx.x * blockDim.x + threadIdx.x; i < TOT4; i += stride) {
        // output linear order: (((b*T + t)*C + c)*HW4 + hw)
        int hw = i % HW4;
        int r  = i / HW4;          // r = (b*T + t)*C + c
        int c  = r % C_;
        int r2 = r / C_;           // r2 = b*T + t
        int t  = r2 % T_;
        int b  = r2 / T_;

        // input linear (float4) index: (((b*C + c)*T + t)*HW4 + hw)
        int base = ((b * C_ + c) * T_ + t) * HW4 + hw;

        float4 ctr = in4[base];
        float4 prv = make_float4(0.f, 0.f, 0.f, 0.f);
        float4 nxt = make_float4(0.f, 0.f, 0.f, 0.f);
        if (t > 0)      prv = in4[base - HW4];
        if (t < T_ - 1) nxt = in4[base + HW4];

        float4 o;
        o.x = fmaf(w0, prv.x, fmaf(w1, ctr.x, fmaf(w2, nxt.x, bs)));
        o.y = fmaf(w0, prv.y, fmaf(w1, ctr.y, fmaf(w2, nxt.y, bs)));
        o.z = fmaf(w0, prv.z, fmaf(w1, ctr.z, fmaf(w2, nxt.z, bs)));
        o.w = fmaf(w0, prv.w, fmaf(w1, ctr.w, fmaf(w2, nxt.w, bs)));
        out4[i] = o;
    }
}

extern "C" void kernel_launch(void* const* d_in, const int* in_sizes, int n_in,
                              void* d_out, int out_size, void* d_ws, size_t ws_size,
                              hipStream_t stream) {
    const float4* in4 = (const float4*)d_in[0];
    const float*  cw  = (const float*)d_in[1];
    const float*  cb  = (const float*)d_in[2];
    float4* out4 = (float4*)d_out;

    const int block = 256;
    const int grid  = 2048;   // grid-stride; ~8 blocks/CU
    temporal_interaction_kernel<<<grid, block, 0, stream>>>(in4, cw, cb, out4);
}

// Round 3
// 37.158 us; speedup vs baseline: 1.4199x; 1.4199x over previous
//
#include <hip/hip_runtime.h>

// x: (B=8, C=128, T=8, H=56, W=56) fp32
// out[b, t, c, h, w] = w0*x[b,c,t-1,h,w] + w1*x[b,c,t,h,w] + w2*x[b,c,t+1,h,w] + bias
// (zero-padded at t boundaries), out shape (B*T, C, H, W) fp32.

typedef float f32x4 __attribute__((ext_vector_type(4)));  // native vec: OK for nontemporal builtin

#define B_   8
#define C_   128
#define T_   8
#define HW4  784                      // (56*56)/4 float4 per plane
#define TOT4 (B_ * T_ * C_ * HW4)     // 6,422,528 float4 outputs
#define UNROLL 4
#define NTH  (TOT4 / UNROLL)          // 1,605,632 threads
#define GRID (NTH / 256)              // 6272 blocks
// NTH == 2 * (C_*T_*HW4)  => stepping i by NTH advances b by exactly 2,
// leaving (t, c, hw) unchanged. So the div/mod + boundary logic hoists.

__global__ __launch_bounds__(256) void temporal_interaction_kernel(
    const f32x4* __restrict__ in4,
    const float* __restrict__ cw,
    const float* __restrict__ cb,
    f32x4* __restrict__ out4)
{
    const float w1 = cw[1];
    const float bs = cb[0];

    const int i0 = blockIdx.x * 256 + threadIdx.x;   // i0 < NTH

    // decompose once: i0 -> (b0 in {0,1}, t, c, hw)
    int hw = i0 % HW4;
    int r  = i0 / HW4;           // (b0*T + t)*C + c
    int c  = r % C_;
    int r2 = r / C_;             // b0*T + t
    int t  = r2 % T_;
    int b0 = r2 / T_;

    // boundary handling without branches: clamp address, zero the weight
    const float wp = (t > 0)      ? cw[0] : 0.f;
    const float wn = (t < T_ - 1) ? cw[2] : 0.f;
    const int   dp = (t > 0)      ? -HW4 : 0;
    const int   dn = (t < T_ - 1) ?  HW4 : 0;

    int base = ((b0 * C_ + c) * T_ + t) * HW4 + hw;  // input float4 index

    #pragma unroll
    for (int k = 0; k < UNROLL; ++k) {
        const int ib = base + k * NTH;       // b advances by 2 per k
        const int io = i0   + k * NTH;       // output linear index

        f32x4 ctr = in4[ib];
        f32x4 prv = in4[ib + dp];
        f32x4 nxt = in4[ib + dn];

        f32x4 o;
        o.x = fmaf(wp, prv.x, fmaf(w1, ctr.x, fmaf(wn, nxt.x, bs)));
        o.y = fmaf(wp, prv.y, fmaf(w1, ctr.y, fmaf(wn, nxt.y, bs)));
        o.z = fmaf(wp, prv.z, fmaf(w1, ctr.z, fmaf(wn, nxt.z, bs)));
        o.w = fmaf(wp, prv.w, fmaf(w1, ctr.w, fmaf(wn, nxt.w, bs)));

        __builtin_nontemporal_store(o, &out4[io]);   // output is never re-read
    }
}

extern "C" void kernel_launch(void* const* d_in, const int* in_sizes, int n_in,
                              void* d_out, int out_size, void* d_ws, size_t ws_size,
                              hipStream_t stream) {
    const f32x4* in4 = (const f32x4*)d_in[0];
    const float* cw  = (const float*)d_in[1];
    const float* cb  = (const float*)d_in[2];
    f32x4* out4 = (f32x4*)d_out;

    temporal_interaction_kernel<<<GRID, 256, 0, stream>>>(in4, cw, cb, out4);
}

// Round 4
// 34.876 us; speedup vs baseline: 1.5127x; 1.0654x over previous
//
#include <hip/hip_runtime.h>

// x: (B=8, C=128, T=8, H=56, W=56) fp32
// out[b, t, c, h, w] = w0*x[b,c,t-1,h,w] + w1*x[b,c,t,h,w] + w2*x[b,c,t+1,h,w] + bias
// (zero-padded at t boundaries), out shape (B*T, C, H, W) fp32.
//
// Each thread owns one full T-column: fixed (b, c, hw4), loads all 8 temporal
// planes into registers up-front (8 independent loads in flight), computes the
// 3-tap filter entirely in registers, stores 8 outputs (nontemporal).

typedef float f32x4 __attribute__((ext_vector_type(4)));

#define B_   8
#define C_   128
#define T_   8
#define HW4  784                       // (56*56)/4 float4 per plane
#define NTH  (B_ * C_ * HW4)           // 802,816 threads (one per T-column)
#define GRID (NTH / 256)               // 3136 blocks, exact fit

__global__ __launch_bounds__(256) void temporal_interaction_kernel(
    const f32x4* __restrict__ in4,
    const float* __restrict__ cw,
    const float* __restrict__ cb,
    f32x4* __restrict__ out4)
{
    const float w0 = cw[0];
    const float w1 = cw[1];
    const float w2 = cw[2];
    const float bs = cb[0];

    const int i0 = blockIdx.x * 256 + threadIdx.x;   // i0 < NTH
    const int hw = i0 % HW4;
    const int bc = i0 / HW4;          // b*C + c
    const int b  = bc / C_;
    const int c  = bc % C_;

    // input column base: (((b*C + c)*T + 0)*HW4 + hw)
    const f32x4* src = in4 + bc * (T_ * HW4) + hw;

    // load the whole temporal column into registers (8 independent loads)
    f32x4 x[T_];
    #pragma unroll
    for (int t = 0; t < T_; ++t) x[t] = src[t * HW4];

    // output base for t=0: ((b*T + 0)*C + c)*HW4 + hw; stride C_*HW4 per t
    const int obase = (b * T_ * C_ + c) * HW4 + hw;

    #pragma unroll
    for (int t = 0; t < T_; ++t) {
        f32x4 o;
        const float px = (t > 0)      ? 1.f : 0.f;   // folded below via selects
        const float nx = (t < T_ - 1) ? 1.f : 0.f;
        const f32x4 prv = (t > 0)      ? x[t - 1] : (f32x4)(0.f);
        const f32x4 nxt = (t < T_ - 1) ? x[t + 1] : (f32x4)(0.f);
        (void)px; (void)nx;

        o.x = fmaf(w0, prv.x, fmaf(w1, x[t].x, fmaf(w2, nxt.x, bs)));
        o.y = fmaf(w0, prv.y, fmaf(w1, x[t].y, fmaf(w2, nxt.y, bs)));
        o.z = fmaf(w0, prv.z, fmaf(w1, x[t].z, fmaf(w2, nxt.z, bs)));
        o.w = fmaf(w0, prv.w, fmaf(w1, x[t].w, fmaf(w2, nxt.w, bs)));

        __builtin_nontemporal_store(o, &out4[obase + t * (C_ * HW4)]);
    }
}

extern "C" void kernel_launch(void* const* d_in, const int* in_sizes, int n_in,
                              void* d_out, int out_size, void* d_ws, size_t ws_size,
                              hipStream_t stream) {
    const f32x4* in4 = (const f32x4*)d_in[0];
    const float* cw  = (const float*)d_in[1];
    const float* cb  = (const float*)d_in[2];
    f32x4* out4 = (f32x4*)d_out;

    temporal_interaction_kernel<<<GRID, 256, 0, stream>>>(in4, cw, cb, out4);
}